// Round 4
// baseline (665.200 us; speedup 1.0000x reference)
//
#include <hip/hip_runtime.h>
#include <math.h>

constexpr float EPS = 1e-5f;
constexpr float SCALE = 0.08838834764831845f; // 1/sqrt(128)

using f32x4  = __attribute__((ext_vector_type(4))) float;
using bf16x8 = __attribute__((ext_vector_type(8))) short;
using us8    = __attribute__((ext_vector_type(8))) unsigned short;

__device__ __forceinline__ unsigned short f2b_rne(float f) {
    unsigned int x = __float_as_uint(f);
    return (unsigned short)((x + 0x7fffu + ((x >> 16) & 1u)) >> 16);
}

// ================= one-time weight split: fp32 -> (hi, lo) bf16 planes =======
// Wp (24576) | Wk (16384) | Wv (16384) packed contiguously.
__global__ __launch_bounds__(256) void split_weights_kernel(
    const float* __restrict__ Wp, const float* __restrict__ Wk,
    const float* __restrict__ Wv, unsigned short* __restrict__ hi,
    unsigned short* __restrict__ lo)
{
    int idx = blockIdx.x * 256 + threadIdx.x; // 57344 total
    float v;
    if (idx < 24576)      v = Wp[idx];
    else if (idx < 40960) v = Wk[idx - 24576];
    else                  v = Wv[idx - 40960];
    unsigned int bits = __float_as_uint(v);
    hi[idx] = (unsigned short)(bits >> 16);
    lo[idx] = f2b_rne(v - __uint_as_float(bits & 0xffff0000u));
}

// ====== GEMM1: inputs = LN(patch @ Wp^T + bp) -> hi/lo bf16 planes ===========
// Weights staged in LDS ONCE; A streamed global->regs (no K-loop barriers).
// Split-precision: 3 MFMAs per product (hh+hl+lh) -> ~fp32 accuracy.
__global__ __launch_bounds__(256, 1) void gemm1_kernel(
    const float* __restrict__ patch,
    const unsigned short* __restrict__ wp_hi, const unsigned short* __restrict__ wp_lo,
    const float* __restrict__ bias, const float* __restrict__ gamma,
    const float* __restrict__ beta,
    unsigned short* __restrict__ out_hi, unsigned short* __restrict__ out_lo)
{
    __shared__ __align__(16) unsigned short Bh[24576], Bl[24576]; // [kb][n][32]

    const int tid  = threadIdx.x;
    const int lane = tid & 63, wave = tid >> 6;
    const int ln15 = lane & 15, quad = lane >> 4;
    const int m0   = blockIdx.x * 128;
    const int wrow = wave * 32;

    // stage Wp hi/lo (128 rows x 192) -> [kb][n][32] layout
    for (int c = tid; c < 3072; c += 256) {
        int n = c / 24, kq = (c % 24) * 8;
        int kb = kq >> 5, j = kq & 31;
        int dst = (kb * 128 + n) * 32 + j;
        int src = n * 192 + kq;
        *(us8*)&Bh[dst] = *(const us8*)&wp_hi[src];
        *(us8*)&Bl[dst] = *(const us8*)&wp_lo[src];
    }
    __syncthreads();

    f32x4 acc[2][8];
#pragma unroll
    for (int mt = 0; mt < 2; mt++)
#pragma unroll
        for (int nt = 0; nt < 8; nt++)
#pragma unroll
            for (int r = 0; r < 4; r++) acc[mt][nt][r] = 0.f;

#pragma unroll
    for (int kb = 0; kb < 6; kb++) {
        bf16x8 ah[2], al[2];
#pragma unroll
        for (int mt = 0; mt < 2; mt++) {
            const float* ap = patch + (size_t)(m0 + wrow + mt * 16 + ln15) * 192
                              + kb * 32 + quad * 8;
            float4 x = *(const float4*)ap;
            float4 y = *(const float4*)(ap + 4);
            float vv[8] = {x.x, x.y, x.z, x.w, y.x, y.y, y.z, y.w};
            us8 h, l;
#pragma unroll
            for (int j = 0; j < 8; j++) {
                unsigned int bits = __float_as_uint(vv[j]);
                h[j] = (unsigned short)(bits >> 16);
                l[j] = f2b_rne(vv[j] - __uint_as_float(bits & 0xffff0000u));
            }
            ah[mt] = (bf16x8)h; al[mt] = (bf16x8)l;
        }
#pragma unroll
        for (int nt = 0; nt < 8; nt++) {
            int o = (kb * 128 + nt * 16 + ln15) * 32 + quad * 8;
            bf16x8 bh = *(const bf16x8*)&Bh[o];
            bf16x8 bl = *(const bf16x8*)&Bl[o];
#pragma unroll
            for (int mt = 0; mt < 2; mt++) {
                acc[mt][nt] = __builtin_amdgcn_mfma_f32_16x16x32_bf16(ah[mt], bh, acc[mt][nt], 0, 0, 0);
                acc[mt][nt] = __builtin_amdgcn_mfma_f32_16x16x32_bf16(ah[mt], bl, acc[mt][nt], 0, 0, 0);
                acc[mt][nt] = __builtin_amdgcn_mfma_f32_16x16x32_bf16(al[mt], bh, acc[mt][nt], 0, 0, 0);
            }
        }
    }

    // epilogue: bias + LN -> split-store
    float bb[8], gg[8], be[8];
#pragma unroll
    for (int nt = 0; nt < 8; nt++) {
        int col = nt * 16 + ln15;
        bb[nt] = bias[col]; gg[nt] = gamma[col]; be[nt] = beta[col];
    }
#pragma unroll
    for (int mt = 0; mt < 2; mt++)
#pragma unroll
        for (int nt = 0; nt < 8; nt++)
#pragma unroll
            for (int r = 0; r < 4; r++) acc[mt][nt][r] += bb[nt];

    float mu[2][4], rs[2][4];
#pragma unroll
    for (int mt = 0; mt < 2; mt++)
#pragma unroll
        for (int r = 0; r < 4; r++) {
            float s = 0.f, s2 = 0.f;
#pragma unroll
            for (int nt = 0; nt < 8; nt++) {
                float v = acc[mt][nt][r];
                s += v; s2 += v * v;
            }
#pragma unroll
            for (int off = 1; off < 16; off <<= 1) {
                s  += __shfl_xor(s,  off, 64);
                s2 += __shfl_xor(s2, off, 64);
            }
            float m = s * (1.f / 128.f);
            mu[mt][r] = m;
            rs[mt][r] = rsqrtf(s2 * (1.f / 128.f) - m * m + EPS);
        }

#pragma unroll
    for (int mt = 0; mt < 2; mt++)
#pragma unroll
        for (int nt = 0; nt < 8; nt++)
#pragma unroll
            for (int r = 0; r < 4; r++) {
                float v = (acc[mt][nt][r] - mu[mt][r]) * rs[mt][r] * gg[nt] + be[nt];
                size_t o = (size_t)(m0 + wrow + mt * 16 + quad * 4 + r) * 128 + nt * 16 + ln15;
                unsigned int bits = __float_as_uint(v);
                out_hi[o] = (unsigned short)(bits >> 16);
                out_lo[o] = f2b_rne(v - __uint_as_float(bits & 0xffff0000u));
            }
}

// ====== fused GEMM k&v: k = A@Wk^T+bk, v = A@Wv^T+bv (A = inputs hi/lo) ======
__global__ __launch_bounds__(256, 1) void gemm_kv_kernel(
    const unsigned short* __restrict__ a_hi, const unsigned short* __restrict__ a_lo,
    const unsigned short* __restrict__ wk_hi, const unsigned short* __restrict__ wk_lo,
    const unsigned short* __restrict__ wv_hi, const unsigned short* __restrict__ wv_lo,
    const float* __restrict__ bk, const float* __restrict__ bv,
    float* __restrict__ kout, float* __restrict__ vout)
{
    __shared__ __align__(16) unsigned short Kh[16384], Kl[16384];
    __shared__ __align__(16) unsigned short Vh[16384], Vl[16384];

    const int tid  = threadIdx.x;
    const int lane = tid & 63, wave = tid >> 6;
    const int ln15 = lane & 15, quad = lane >> 4;
    const int m0   = blockIdx.x * 128;
    const int wrow = wave * 32;

    for (int c = tid; c < 2048; c += 256) {
        int n = c >> 4, kq = (c & 15) * 8;
        int kb = kq >> 5, j = kq & 31;
        int dst = (kb * 128 + n) * 32 + j;
        int src = n * 128 + kq;
        *(us8*)&Kh[dst] = *(const us8*)&wk_hi[src];
        *(us8*)&Kl[dst] = *(const us8*)&wk_lo[src];
        *(us8*)&Vh[dst] = *(const us8*)&wv_hi[src];
        *(us8*)&Vl[dst] = *(const us8*)&wv_lo[src];
    }
    __syncthreads();

    f32x4 acc[2][16];
#pragma unroll
    for (int mt = 0; mt < 2; mt++)
#pragma unroll
        for (int nt = 0; nt < 16; nt++)
#pragma unroll
            for (int r = 0; r < 4; r++) acc[mt][nt][r] = 0.f;

#pragma unroll
    for (int kb = 0; kb < 4; kb++) {
        bf16x8 ah[2], al[2];
#pragma unroll
        for (int mt = 0; mt < 2; mt++) {
            size_t aoff = (size_t)(m0 + wrow + mt * 16 + ln15) * 128 + kb * 32 + quad * 8;
            ah[mt] = *(const bf16x8*)&a_hi[aoff];
            al[mt] = *(const bf16x8*)&a_lo[aoff];
        }
#pragma unroll
        for (int nt = 0; nt < 8; nt++) {
            int o = (kb * 128 + nt * 16 + ln15) * 32 + quad * 8;
            bf16x8 kh = *(const bf16x8*)&Kh[o];
            bf16x8 kl = *(const bf16x8*)&Kl[o];
            bf16x8 vh = *(const bf16x8*)&Vh[o];
            bf16x8 vl = *(const bf16x8*)&Vl[o];
#pragma unroll
            for (int mt = 0; mt < 2; mt++) {
                acc[mt][nt] = __builtin_amdgcn_mfma_f32_16x16x32_bf16(ah[mt], kh, acc[mt][nt], 0, 0, 0);
                acc[mt][nt] = __builtin_amdgcn_mfma_f32_16x16x32_bf16(ah[mt], kl, acc[mt][nt], 0, 0, 0);
                acc[mt][nt] = __builtin_amdgcn_mfma_f32_16x16x32_bf16(al[mt], kh, acc[mt][nt], 0, 0, 0);
                acc[mt][8+nt] = __builtin_amdgcn_mfma_f32_16x16x32_bf16(ah[mt], vh, acc[mt][8+nt], 0, 0, 0);
                acc[mt][8+nt] = __builtin_amdgcn_mfma_f32_16x16x32_bf16(ah[mt], vl, acc[mt][8+nt], 0, 0, 0);
                acc[mt][8+nt] = __builtin_amdgcn_mfma_f32_16x16x32_bf16(al[mt], vh, acc[mt][8+nt], 0, 0, 0);
            }
        }
    }

    float bbk[8], bbv[8];
#pragma unroll
    for (int nt = 0; nt < 8; nt++) {
        int col = nt * 16 + ln15;
        bbk[nt] = bk[col]; bbv[nt] = bv[col];
    }
#pragma unroll
    for (int mt = 0; mt < 2; mt++)
#pragma unroll
        for (int nt = 0; nt < 16; nt++) {
            int col = (nt & 7) * 16 + ln15;
            float bbias = (nt < 8) ? bbk[nt] : bbv[nt - 8];
            float* dst = (nt < 8) ? kout : vout;
#pragma unroll
            for (int r = 0; r < 4; r++) {
                size_t row = (size_t)(m0 + wrow + mt * 16 + quad * 4 + r);
                dst[row * 128 + col] = acc[mt][nt][r] + bbias;
            }
        }
}

// ====== persistent per-batch slot loop: init + 3x(attn + GRU + MLP + q) ======
// One block per batch (iterations independent across batches -> no global sync).
__global__ __launch_bounds__(1024) void slot_iter_kernel(
    const float* __restrict__ noise, const float* __restrict__ smu,
    const float* __restrict__ sls, const float* __restrict__ g_s,
    const float* __restrict__ b_s, const float* __restrict__ Wq,
    const float* __restrict__ bq,
    const float* __restrict__ kbuf, const float* __restrict__ vbuf,
    const float* __restrict__ Wih, const float* __restrict__ bih,
    const float* __restrict__ Whh, const float* __restrict__ bhh,
    const float* __restrict__ g_m, const float* __restrict__ b_m,
    const float* __restrict__ W1, const float* __restrict__ b1,
    const float* __restrict__ W2, const float* __restrict__ b2,
    float* __restrict__ out_slots, float* __restrict__ out_attn)
{
    __shared__ float q_l[3][128];
    __shared__ float slots_l[3][128];
    __shared__ float u_l[3][128];
    __shared__ float hnew_l[3][128];
    __shared__ float nrm_l[3][128];
    __shared__ float hid_l[3][256];
    __shared__ float lg_l[3][1024];
    __shared__ float wsm[3][1024];
    __shared__ float upd8[8][3][128];
    __shared__ float redA[16], redB[16];

    const int b = blockIdx.x, tid = threadIdx.x;
    const int s3 = tid >> 7;        // slot row, valid for tid<384
    const int d  = tid & 127;

    // per-row LayerNorm across threads tid<384 (rows are wave-aligned pairs)
    auto rowln = [&](float val, const float* g, const float* be_) -> float {
        float s1 = val, s2 = val * val;
#pragma unroll
        for (int off = 32; off >= 1; off >>= 1) {
            s1 += __shfl_down(s1, off, 64);
            s2 += __shfl_down(s2, off, 64);
        }
        if (tid < 384 && (tid & 63) == 0) { redA[tid >> 6] = s1; redB[tid >> 6] = s2; }
        __syncthreads();
        float outv = 0.f;
        if (tid < 384) {
            float S  = redA[2 * s3] + redA[2 * s3 + 1];
            float S2 = redB[2 * s3] + redB[2 * s3 + 1];
            float m = S * (1.f / 128.f);
            float r = rsqrtf(S2 * (1.f / 128.f) - m * m + EPS);
            outv = (val - m) * r * g[d] + be_[d];
        }
        __syncthreads();
        return outv;
    };
    // q[s][j] = bq[j] + sum_d nrm_l[s][d] * Wq[j][d]   (thread = (s,j)=(s3,d))
    auto qcalc = [&]() {
        if (tid < 384) {
            const float4* wr = (const float4*)&Wq[(size_t)d * 128];
            const float* x = nrm_l[s3];
            float a = bq[d];
#pragma unroll 8
            for (int d4 = 0; d4 < 32; d4++) {
                float4 w = wr[d4];
                a += x[4*d4]*w.x + x[4*d4+1]*w.y + x[4*d4+2]*w.z + x[4*d4+3]*w.w;
            }
            q_l[s3][d] = a;
        }
    };

    // ---- init slots + LN + q0 ----
    float x0 = 0.f;
    if (tid < 384) {
        x0 = smu[tid] + expf(sls[tid]) * noise[(size_t)b * 384 + tid];
        slots_l[s3][d] = x0;
    }
    float nrm = rowln(x0, g_s, b_s);
    if (tid < 384) nrm_l[s3][d] = nrm;
    __syncthreads();
    qcalc();
    __syncthreads();

    const int p = tid & 7;          // logits: 16-dim slice owner
    for (int it = 0; it < 3; ++it) {
        // cache this iter's q fragment (p*16 .. p*16+15 of each slot) in regs
        float4 qr[12];
#pragma unroll
        for (int s = 0; s < 3; s++) {
            const float4* qp = (const float4*)&q_l[s][p * 16];
#pragma unroll
            for (int i = 0; i < 4; i++) qr[s * 4 + i] = qp[i];
        }
#pragma unroll
        for (int j = 0; j < 3; j++) ((float*)upd8)[tid + j * 1024] = 0.f;
        __syncthreads();

        // ---- logits: 8 rounds x (128 tokens x 8 dim-slices), k from global ----
        for (int r8 = 0; r8 < 8; ++r8) {
            int t = r8 * 128 + (tid >> 3);
            const float4* k4 = (const float4*)(kbuf + ((size_t)b * 1024 + t) * 128 + p * 16);
            float p0 = 0.f, p1 = 0.f, p2 = 0.f;
#pragma unroll
            for (int i = 0; i < 4; i++) {
                float4 kk = k4[i];
                p0 += qr[i].x*kk.x + qr[i].y*kk.y + qr[i].z*kk.z + qr[i].w*kk.w;
                p1 += qr[4+i].x*kk.x + qr[4+i].y*kk.y + qr[4+i].z*kk.z + qr[4+i].w*kk.w;
                p2 += qr[8+i].x*kk.x + qr[8+i].y*kk.y + qr[8+i].z*kk.z + qr[8+i].w*kk.w;
            }
            p0 += __shfl_xor(p0, 1, 64); p0 += __shfl_xor(p0, 2, 64); p0 += __shfl_xor(p0, 4, 64);
            p1 += __shfl_xor(p1, 1, 64); p1 += __shfl_xor(p1, 2, 64); p1 += __shfl_xor(p1, 4, 64);
            p2 += __shfl_xor(p2, 1, 64); p2 += __shfl_xor(p2, 2, 64); p2 += __shfl_xor(p2, 4, 64);
            if (p == 0) {
                lg_l[0][t] = p0 * SCALE; lg_l[1][t] = p1 * SCALE; lg_l[2][t] = p2 * SCALE;
            }
        }
        __syncthreads();

        // ---- softmax over slots, one token per thread ----
        {
            int t = tid;
            float l0 = lg_l[0][t], l1 = lg_l[1][t], l2 = lg_l[2][t];
            float m = fmaxf(l0, fmaxf(l1, l2));
            float e0 = expf(l0 - m), e1 = expf(l1 - m), e2 = expf(l2 - m);
            float inv = 1.f / (e0 + e1 + e2);
            wsm[0][t] = e0 * inv; wsm[1][t] = e1 * inv; wsm[2][t] = e2 * inv;
            if (it == 2) {
                out_attn[b * 3072 + t]        = e0 * inv;
                out_attn[b * 3072 + 1024 + t] = e1 * inv;
                out_attn[b * 3072 + 2048 + t] = e2 * inv;
            }
        }
        __syncthreads();

        // ---- PV: thread = (token-eighth h, dim dd); v from global, coalesced ----
        {
            int h = tid >> 7, dd = tid & 127;
            const float* vp = vbuf + ((size_t)b * 1024 + h * 128) * 128 + dd;
            const float* w0 = &wsm[0][h * 128];
            const float* w1 = &wsm[1][h * 128];
            const float* w2 = &wsm[2][h * 128];
            float a0 = 0.f, a1 = 0.f, a2 = 0.f;
#pragma unroll 8
            for (int t = 0; t < 128; t++) {
                float vv = vp[(size_t)t * 128];
                a0 += w0[t] * vv; a1 += w1[t] * vv; a2 += w2[t] * vv;
            }
            upd8[h][0][dd] = a0; upd8[h][1][dd] = a1; upd8[h][2][dd] = a2;
        }
        __syncthreads();
        if (tid < 384) {
            float u = 0.f;
#pragma unroll
            for (int h = 0; h < 8; h++) u += upd8[h][s3][d];
            u_l[s3][d] = u;
        }
        __syncthreads();

        // ---- GRU cell (thread = (s3,d)) ----
        float hnew = 0.f;
        if (tid < 384) {
            const float* u = u_l[s3];
            const float* hh = slots_l[s3];
            float hprev = hh[d];
            float ir = bih[d], iz = bih[128 + d], in_ = bih[256 + d];
            float hr = bhh[d], hz = bhh[128 + d], hn = bhh[256 + d];
            const float4* wi0 = (const float4*)&Wih[(size_t)d * 128];
            const float4* wi1 = (const float4*)&Wih[(size_t)(128 + d) * 128];
            const float4* wi2 = (const float4*)&Wih[(size_t)(256 + d) * 128];
            const float4* wh0 = (const float4*)&Whh[(size_t)d * 128];
            const float4* wh1 = (const float4*)&Whh[(size_t)(128 + d) * 128];
            const float4* wh2 = (const float4*)&Whh[(size_t)(256 + d) * 128];
#pragma unroll 4
            for (int d4 = 0; d4 < 32; d4++) {
                float u0 = u[4*d4], u1 = u[4*d4+1], u2 = u[4*d4+2], u3 = u[4*d4+3];
                float h0 = hh[4*d4], h1 = hh[4*d4+1], h2 = hh[4*d4+2], h3 = hh[4*d4+3];
                float4 w;
                w = wi0[d4]; ir  += u0*w.x + u1*w.y + u2*w.z + u3*w.w;
                w = wi1[d4]; iz  += u0*w.x + u1*w.y + u2*w.z + u3*w.w;
                w = wi2[d4]; in_ += u0*w.x + u1*w.y + u2*w.z + u3*w.w;
                w = wh0[d4]; hr  += h0*w.x + h1*w.y + h2*w.z + h3*w.w;
                w = wh1[d4]; hz  += h0*w.x + h1*w.y + h2*w.z + h3*w.w;
                w = wh2[d4]; hn  += h0*w.x + h1*w.y + h2*w.z + h3*w.w;
            }
            float r = 1.f / (1.f + expf(-(ir + hr)));
            float z = 1.f / (1.f + expf(-(iz + hz)));
            float nn = tanhf(in_ + r * hn);
            hnew = (1.f - z) * nn + z * hprev;
            hnew_l[s3][d] = hnew;
        }
        __syncthreads();

        // ---- LN(g_m) -> MLP1+GELU -> MLP2 + residual ----
        float mn = rowln(hnew, g_m, b_m);
        if (tid < 384) nrm_l[s3][d] = mn;
        __syncthreads();
        if (tid < 384) {
            const float* x = nrm_l[s3];
            float a0 = b1[d], a1 = b1[128 + d];
            const float4* w1a = (const float4*)&W1[(size_t)d * 128];
            const float4* w1b = (const float4*)&W1[(size_t)(128 + d) * 128];
#pragma unroll 4
            for (int d4 = 0; d4 < 32; d4++) {
                float x0_ = x[4*d4], x1 = x[4*d4+1], x2 = x[4*d4+2], x3 = x[4*d4+3];
                float4 wa = w1a[d4], wb = w1b[d4];
                a0 += x0_*wa.x + x1*wa.y + x2*wa.z + x3*wa.w;
                a1 += x0_*wb.x + x1*wb.y + x2*wb.z + x3*wb.w;
            }
            a0 = 0.5f * a0 * (1.f + erff(a0 * 0.70710678118654752f));
            a1 = 0.5f * a1 * (1.f + erff(a1 * 0.70710678118654752f));
            hid_l[s3][d] = a0; hid_l[s3][128 + d] = a1;
        }
        __syncthreads();
        float snew = 0.f;
        if (tid < 384) {
            const float* g = hid_l[s3];
            float o = b2[d];
            const float4* w2r = (const float4*)&W2[(size_t)d * 256];
#pragma unroll 4
            for (int d4 = 0; d4 < 64; d4++) {
                float4 w = w2r[d4];
                o += g[4*d4]*w.x + g[4*d4+1]*w.y + g[4*d4+2]*w.z + g[4*d4+3]*w.w;
            }
            snew = hnew_l[s3][d] + o;
            slots_l[s3][d] = snew;
            if (it == 2) out_slots[(size_t)b * 384 + tid] = snew;
        }
        __syncthreads();

        if (it < 2) { // q for the next iteration
            float nq = rowln(snew, g_s, b_s);
            if (tid < 384) nrm_l[s3][d] = nq;
            __syncthreads();
            qcalc();
            __syncthreads();
        }
    }
}

// ============================================================================
extern "C" void kernel_launch(void* const* d_in, const int* in_sizes, int n_in,
                              void* d_out, int out_size, void* d_ws, size_t ws_size,
                              hipStream_t stream)
{
    const float* patch   = (const float*)d_in[0];
    const float* noise   = (const float*)d_in[1];
    const float* slot_mu = (const float*)d_in[2];
    const float* slot_ls = (const float*)d_in[3];
    const float* Wp = (const float*)d_in[4];  const float* bp = (const float*)d_in[5];
    const float* g_in = (const float*)d_in[6]; const float* b_in = (const float*)d_in[7];
    const float* Wq = (const float*)d_in[8];  const float* bq = (const float*)d_in[9];
    const float* Wk = (const float*)d_in[10]; const float* bk = (const float*)d_in[11];
    const float* Wv = (const float*)d_in[12]; const float* bv = (const float*)d_in[13];
    const float* Wih = (const float*)d_in[14]; const float* bih = (const float*)d_in[15];
    const float* Whh = (const float*)d_in[16]; const float* bhh = (const float*)d_in[17];
    const float* g_s = (const float*)d_in[18]; const float* b_s = (const float*)d_in[19];
    const float* W1 = (const float*)d_in[20]; const float* b1 = (const float*)d_in[21];
    const float* W2 = (const float*)d_in[22]; const float* b2 = (const float*)d_in[23];
    const float* g_m = (const float*)d_in[24]; const float* b_m = (const float*)d_in[25];

    float* kbuf = (float*)d_ws;                                   // 16777216 f32
    float* vbuf = kbuf + 16777216;                                // 16777216 f32
    unsigned short* ln_hi = (unsigned short*)(vbuf + 16777216);   // 16777216 bf16
    unsigned short* ln_lo = ln_hi + 16777216;                     // 16777216 bf16
    unsigned short* w_hi  = ln_lo + 16777216;                     // 57344
    unsigned short* w_lo  = w_hi + 57344;                         // 57344
    unsigned short* wp_hi = w_hi,         * wp_lo = w_lo;
    unsigned short* wk_hi = w_hi + 24576, * wk_lo = w_lo + 24576;
    unsigned short* wv_hi = w_hi + 40960, * wv_lo = w_lo + 40960;

    float* out_slots = (float*)d_out;                             // (B,K,H)
    float* out_attn  = (float*)d_out + 49152;                     // (B,K,N)

    split_weights_kernel<<<224, 256, 0, stream>>>(Wp, Wk, Wv, w_hi, w_lo);
    gemm1_kernel<<<1024, 256, 0, stream>>>(patch, wp_hi, wp_lo, bp, g_in, b_in,
                                           ln_hi, ln_lo);
    gemm_kv_kernel<<<1024, 256, 0, stream>>>(ln_hi, ln_lo, wk_hi, wk_lo,
                                             wv_hi, wv_lo, bk, bv, kbuf, vbuf);
    slot_iter_kernel<<<128, 1024, 0, stream>>>(
        noise, slot_mu, slot_ls, g_s, b_s, Wq, bq, kbuf, vbuf,
        Wih, bih, Whh, bhh, g_m, b_m, W1, b1, W2, b2, out_slots, out_attn);
}

// Round 6
// 513.636 us; speedup vs baseline: 1.2951x; 1.2951x over previous
//
#include <hip/hip_runtime.h>
#include <math.h>

constexpr float EPS = 1e-5f;
constexpr float SCALE = 0.08838834764831845f; // 1/sqrt(128)

using f32x4  = __attribute__((ext_vector_type(4))) float;
using bf16x8 = __attribute__((ext_vector_type(8))) short;
using us8    = __attribute__((ext_vector_type(8))) unsigned short;

__device__ __forceinline__ unsigned short f2b_rne(float f) {
    unsigned int x = __float_as_uint(f);
    return (unsigned short)((x + 0x7fffu + ((x >> 16) & 1u)) >> 16);
}

// ================= one-time weight split: fp32 -> (hi, lo) bf16 planes =======
__global__ __launch_bounds__(256) void split_weights_kernel(
    const float* __restrict__ Wp, const float* __restrict__ Wk,
    const float* __restrict__ Wv, unsigned short* __restrict__ hi,
    unsigned short* __restrict__ lo)
{
    int idx = blockIdx.x * 256 + threadIdx.x; // 57344 total
    float v;
    if (idx < 24576)      v = Wp[idx];
    else if (idx < 40960) v = Wk[idx - 24576];
    else                  v = Wv[idx - 40960];
    unsigned int bits = __float_as_uint(v);
    hi[idx] = (unsigned short)(bits >> 16);
    lo[idx] = f2b_rne(v - __uint_as_float(bits & 0xffff0000u));
}

// ====== GEMM1: inputs = LN(patch @ Wp^T + bp) -> hi/lo bf16 planes ===========
// 512 thr = 8 waves; weights (hi/lo, 96 KB) staged in LDS ONCE; A streamed
// global->regs (barrier-free K loop). Split precision: 3 MFMAs per product.
__global__ __launch_bounds__(512, 2) void gemm1_kernel(
    const float* __restrict__ patch,
    const unsigned short* __restrict__ wp_hi, const unsigned short* __restrict__ wp_lo,
    const float* __restrict__ bias, const float* __restrict__ gamma,
    const float* __restrict__ beta,
    unsigned short* __restrict__ out_hi, unsigned short* __restrict__ out_lo)
{
    __shared__ __align__(16) unsigned short Bh[24576], Bl[24576]; // [kb][n][32]

    const int tid  = threadIdx.x;
    const int lane = tid & 63, w8 = tid >> 6;
    const int ln15 = lane & 15, quad = lane >> 4;
    const int m0   = blockIdx.x * 128;
    const int row  = m0 + w8 * 16 + ln15;

    // stage Wp hi/lo (128 x 192) -> [kb][n][32]
    for (int c = tid; c < 3072; c += 512) {
        int n = c / 24, kq8 = c % 24;
        int kb = kq8 >> 2, j = (kq8 & 3) * 8;
        int dst = (kb * 128 + n) * 32 + j;
        int src = n * 192 + kq8 * 8;
        *(us8*)&Bh[dst] = *(const us8*)&wp_hi[src];
        *(us8*)&Bl[dst] = *(const us8*)&wp_lo[src];
    }
    __syncthreads();

    // A fragments: 6 K-blocks, hi/lo, loaded up-front (independent loads)
    bf16x8 ah[6], al[6];
#pragma unroll
    for (int kb = 0; kb < 6; kb++) {
        const float* ap = patch + (size_t)row * 192 + kb * 32 + quad * 8;
        float4 x = *(const float4*)ap;
        float4 y = *(const float4*)(ap + 4);
        float vv[8] = {x.x, x.y, x.z, x.w, y.x, y.y, y.z, y.w};
        us8 h, l;
#pragma unroll
        for (int j = 0; j < 8; j++) {
            unsigned int bits = __float_as_uint(vv[j]);
            h[j] = (unsigned short)(bits >> 16);
            l[j] = f2b_rne(vv[j] - __uint_as_float(bits & 0xffff0000u));
        }
        ah[kb] = (bf16x8)h; al[kb] = (bf16x8)l;
    }

    f32x4 acc[8];
#pragma unroll
    for (int nt = 0; nt < 8; nt++)
#pragma unroll
        for (int r = 0; r < 4; r++) acc[nt][r] = 0.f;

#pragma unroll
    for (int kb = 0; kb < 6; kb++)
#pragma unroll
        for (int nt = 0; nt < 8; nt++) {
            int o = (kb * 128 + nt * 16 + ln15) * 32 + quad * 8;
            bf16x8 bh = *(const bf16x8*)&Bh[o];
            bf16x8 bl = *(const bf16x8*)&Bl[o];
            acc[nt] = __builtin_amdgcn_mfma_f32_16x16x32_bf16(ah[kb], bh, acc[nt], 0, 0, 0);
            acc[nt] = __builtin_amdgcn_mfma_f32_16x16x32_bf16(ah[kb], bl, acc[nt], 0, 0, 0);
            acc[nt] = __builtin_amdgcn_mfma_f32_16x16x32_bf16(al[kb], bh, acc[nt], 0, 0, 0);
        }

    // epilogue: bias + LN -> split store
    float bb[8], gg[8], be[8];
#pragma unroll
    for (int nt = 0; nt < 8; nt++) {
        int col = nt * 16 + ln15;
        bb[nt] = bias[col]; gg[nt] = gamma[col]; be[nt] = beta[col];
    }
#pragma unroll
    for (int nt = 0; nt < 8; nt++)
#pragma unroll
        for (int r = 0; r < 4; r++) acc[nt][r] += bb[nt];

    float mu[4], rs[4];
#pragma unroll
    for (int r = 0; r < 4; r++) {
        float s = 0.f, s2 = 0.f;
#pragma unroll
        for (int nt = 0; nt < 8; nt++) { float v = acc[nt][r]; s += v; s2 += v * v; }
#pragma unroll
        for (int off = 1; off < 16; off <<= 1) {
            s  += __shfl_xor(s,  off, 64);
            s2 += __shfl_xor(s2, off, 64);
        }
        float m = s * (1.f / 128.f);
        mu[r] = m;
        rs[r] = rsqrtf(s2 * (1.f / 128.f) - m * m + EPS);
    }
#pragma unroll
    for (int nt = 0; nt < 8; nt++)
#pragma unroll
        for (int r = 0; r < 4; r++) {
            float v = (acc[nt][r] - mu[r]) * rs[r] * gg[nt] + be[nt];
            size_t o = (size_t)(m0 + w8 * 16 + quad * 4 + r) * 128 + nt * 16 + ln15;
            unsigned int bits = __float_as_uint(v);
            out_hi[o] = (unsigned short)(bits >> 16);
            out_lo[o] = f2b_rne(v - __uint_as_float(bits & 0xffff0000u));
        }
}

// ====== fused GEMM k&v (A = inputs hi/lo, barrier-free K loop) ===============
__global__ __launch_bounds__(512, 2) void gemm_kv_kernel(
    const unsigned short* __restrict__ a_hi, const unsigned short* __restrict__ a_lo,
    const unsigned short* __restrict__ wk_hi, const unsigned short* __restrict__ wk_lo,
    const unsigned short* __restrict__ wv_hi, const unsigned short* __restrict__ wv_lo,
    const float* __restrict__ bk, const float* __restrict__ bv,
    float* __restrict__ kout, float* __restrict__ vout)
{
    __shared__ __align__(16) unsigned short Kh[16384], Kl[16384];
    __shared__ __align__(16) unsigned short Vh[16384], Vl[16384];

    const int tid  = threadIdx.x;
    const int lane = tid & 63, w8 = tid >> 6;
    const int ln15 = lane & 15, quad = lane >> 4;
    const int m0   = blockIdx.x * 128;
    const int row  = m0 + w8 * 16 + ln15;

    for (int c = tid; c < 2048; c += 512) {
        int n = c >> 4, kq8 = c & 15;
        int kb = kq8 >> 2, j = (kq8 & 3) * 8;
        int dst = (kb * 128 + n) * 32 + j;
        int src = n * 128 + kq8 * 8;
        *(us8*)&Kh[dst] = *(const us8*)&wk_hi[src];
        *(us8*)&Kl[dst] = *(const us8*)&wk_lo[src];
        *(us8*)&Vh[dst] = *(const us8*)&wv_hi[src];
        *(us8*)&Vl[dst] = *(const us8*)&wv_lo[src];
    }
    __syncthreads();

    bf16x8 ah[4], al[4];
#pragma unroll
    for (int kb = 0; kb < 4; kb++) {
        size_t aoff = (size_t)row * 128 + kb * 32 + quad * 8;
        ah[kb] = *(const bf16x8*)&a_hi[aoff];
        al[kb] = *(const bf16x8*)&a_lo[aoff];
    }

    f32x4 acc[16];
#pragma unroll
    for (int nt = 0; nt < 16; nt++)
#pragma unroll
        for (int r = 0; r < 4; r++) acc[nt][r] = 0.f;

#pragma unroll
    for (int kb = 0; kb < 4; kb++)
#pragma unroll
        for (int nt = 0; nt < 8; nt++) {
            int o = (kb * 128 + nt * 16 + ln15) * 32 + quad * 8;
            bf16x8 kh = *(const bf16x8*)&Kh[o];
            bf16x8 kl = *(const bf16x8*)&Kl[o];
            bf16x8 vh = *(const bf16x8*)&Vh[o];
            bf16x8 vl = *(const bf16x8*)&Vl[o];
            acc[nt] = __builtin_amdgcn_mfma_f32_16x16x32_bf16(ah[kb], kh, acc[nt], 0, 0, 0);
            acc[nt] = __builtin_amdgcn_mfma_f32_16x16x32_bf16(ah[kb], kl, acc[nt], 0, 0, 0);
            acc[nt] = __builtin_amdgcn_mfma_f32_16x16x32_bf16(al[kb], kh, acc[nt], 0, 0, 0);
            acc[8+nt] = __builtin_amdgcn_mfma_f32_16x16x32_bf16(ah[kb], vh, acc[8+nt], 0, 0, 0);
            acc[8+nt] = __builtin_amdgcn_mfma_f32_16x16x32_bf16(ah[kb], vl, acc[8+nt], 0, 0, 0);
            acc[8+nt] = __builtin_amdgcn_mfma_f32_16x16x32_bf16(al[kb], vh, acc[8+nt], 0, 0, 0);
        }

    float bbk[8], bbv[8];
#pragma unroll
    for (int nt = 0; nt < 8; nt++) {
        int col = nt * 16 + ln15;
        bbk[nt] = bk[col]; bbv[nt] = bv[col];
    }
#pragma unroll
    for (int nt = 0; nt < 16; nt++) {
        int col = (nt & 7) * 16 + ln15;
        float bbias = (nt < 8) ? bbk[nt] : bbv[nt - 8];
        float* dst = (nt < 8) ? kout : vout;
#pragma unroll
        for (int r = 0; r < 4; r++) {
            size_t rr = (size_t)(m0 + w8 * 16 + quad * 4 + r);
            dst[rr * 128 + col] = acc[nt][r] + bbias;
        }
    }
}

// =================== init slots + LN + q0 ====================================
__global__ __launch_bounds__(128) void init_lnq_kernel(
    const float* __restrict__ noise, const float* __restrict__ smu,
    const float* __restrict__ sls, const float* __restrict__ g_s,
    const float* __restrict__ b_s, const float* __restrict__ Wq,
    const float* __restrict__ bq, float* __restrict__ slots,
    float* __restrict__ q)
{
    __shared__ float s_l[128];
    __shared__ float red[4];
    const int row = blockIdx.x, tid = threadIdx.x;
    const int k = row % 3;
    float x = smu[k * 128 + tid] + expf(sls[k * 128 + tid]) * noise[row * 128 + tid];
    slots[row * 128 + tid] = x;

    float s = x, s2 = x * x;
#pragma unroll
    for (int off = 32; off >= 1; off >>= 1) {
        s += __shfl_down(s, off, 64); s2 += __shfl_down(s2, off, 64);
    }
    if ((tid & 63) == 0) { red[tid >> 6] = s; red[2 + (tid >> 6)] = s2; }
    __syncthreads();
    float S = red[0] + red[1], S2 = red[2] + red[3];
    float m = S * (1.f / 128.f);
    float r = rsqrtf(S2 * (1.f / 128.f) - m * m + EPS);
    s_l[tid] = (x - m) * r * g_s[tid] + b_s[tid];
    __syncthreads();

    const float4* wr = (const float4*)&Wq[(size_t)tid * 128];
    float a = bq[tid];
#pragma unroll 8
    for (int d4 = 0; d4 < 32; d4++) {
        float4 w = wr[d4];
        a += s_l[4 * d4] * w.x + s_l[4 * d4 + 1] * w.y
           + s_l[4 * d4 + 2] * w.z + s_l[4 * d4 + 3] * w.w;
    }
    q[row * 128 + tid] = a;
}

// ============ attention: 32-token chunks, 4096 blocks x 256 thr ==============
__global__ __launch_bounds__(256) void attn_kernel(
    const float* __restrict__ q, const float* __restrict__ kbuf,
    const float* __restrict__ vbuf, float* __restrict__ upd_part,
    float* __restrict__ attn_out, int write_attn)
{
    __shared__ float q_l[3][128];
    __shared__ __align__(16) float k_l[32][132];
    __shared__ __align__(16) float v_l[32][132];
    __shared__ float lg[3][32];
    __shared__ float w_l[3][32];
    __shared__ float pp[2][3][128];
    const int b = blockIdx.y, chunk = blockIdx.x, n0 = chunk * 32, tid = threadIdx.x;

    for (int idx = tid; idx < 384; idx += 256)
        q_l[idx >> 7][idx & 127] = q[b * 384 + idx];

    const float4* kg = (const float4*)(kbuf + ((size_t)b * 1024 + n0) * 128);
    const float4* vg = (const float4*)(vbuf + ((size_t)b * 1024 + n0) * 128);
    for (int idx = tid; idx < 1024; idx += 256) {
        int n = idx >> 5, c = (idx & 31) * 4;
        *(float4*)&k_l[n][c] = kg[idx];
        *(float4*)&v_l[n][c] = vg[idx];
    }
    __syncthreads();

    { // logits: thread = (token t, 16-dim slice p); all 256 active
        int t = tid >> 3, p = tid & 7;
        const float4* kr = (const float4*)&k_l[t][p * 16];
        const float4* q0 = (const float4*)&q_l[0][p * 16];
        const float4* q1 = (const float4*)&q_l[1][p * 16];
        const float4* q2 = (const float4*)&q_l[2][p * 16];
        float p0 = 0.f, p1 = 0.f, p2 = 0.f;
#pragma unroll
        for (int i = 0; i < 4; i++) {
            float4 kk = kr[i];
            float4 a = q0[i], c = q1[i], e = q2[i];
            p0 += a.x*kk.x + a.y*kk.y + a.z*kk.z + a.w*kk.w;
            p1 += c.x*kk.x + c.y*kk.y + c.z*kk.z + c.w*kk.w;
            p2 += e.x*kk.x + e.y*kk.y + e.z*kk.z + e.w*kk.w;
        }
        p0 += __shfl_xor(p0, 1, 64); p0 += __shfl_xor(p0, 2, 64); p0 += __shfl_xor(p0, 4, 64);
        p1 += __shfl_xor(p1, 1, 64); p1 += __shfl_xor(p1, 2, 64); p1 += __shfl_xor(p1, 4, 64);
        p2 += __shfl_xor(p2, 1, 64); p2 += __shfl_xor(p2, 2, 64); p2 += __shfl_xor(p2, 4, 64);
        if (p == 0) {
            lg[0][t] = p0 * SCALE; lg[1][t] = p1 * SCALE; lg[2][t] = p2 * SCALE;
        }
    }
    __syncthreads();

    if (tid < 32) { // softmax over the 3 slots
        float l0 = lg[0][tid], l1 = lg[1][tid], l2 = lg[2][tid];
        float m = fmaxf(l0, fmaxf(l1, l2));
        float e0 = expf(l0 - m), e1 = expf(l1 - m), e2 = expf(l2 - m);
        float inv = 1.f / (e0 + e1 + e2);
        w_l[0][tid] = e0 * inv; w_l[1][tid] = e1 * inv; w_l[2][tid] = e2 * inv;
        if (write_attn) {
            attn_out[b * 3072 + n0 + tid]        = e0 * inv;
            attn_out[b * 3072 + 1024 + n0 + tid] = e1 * inv;
            attn_out[b * 3072 + 2048 + n0 + tid] = e2 * inv;
        }
    }
    __syncthreads();

    { // PV: thread = (dim d, token-half h); all 256 active
        int d = tid & 127, h = tid >> 7;
        float a0 = 0.f, a1 = 0.f, a2 = 0.f;
#pragma unroll
        for (int i = 0; i < 16; i++) {
            int t = h * 16 + i;
            float vv = v_l[t][d];
            a0 += w_l[0][t] * vv; a1 += w_l[1][t] * vv; a2 += w_l[2][t] * vv;
        }
        pp[h][0][d] = a0; pp[h][1][d] = a1; pp[h][2][d] = a2;
    }
    __syncthreads();

    // FIX (round 5 bug): blockDim=256, but 384 values must be stored.
    // The old `if (tid < 384)` dropped slot 2 entirely -> poison updates.
    for (int idx = tid; idx < 384; idx += 256) {
        int s = idx >> 7, d = idx & 127;
        upd_part[(((size_t)b * 32 + chunk) * 3 + s) * 128 + d] =
            pp[0][s][d] + pp[1][s][d];
    }
}

// ====== slot update: GRU + LN + MLP + residual (+ LN_s + q), 256 thr/row =====
__global__ __launch_bounds__(256) void slot_update_kernel(
    const float* __restrict__ slots_in, const float* __restrict__ upd_part,
    const float* __restrict__ Wih, const float* __restrict__ bih,
    const float* __restrict__ Whh, const float* __restrict__ bhh,
    const float* __restrict__ g_m, const float* __restrict__ b_m,
    const float* __restrict__ W1, const float* __restrict__ b1,
    const float* __restrict__ W2, const float* __restrict__ b2,
    const float* __restrict__ g_s, const float* __restrict__ b_s,
    const float* __restrict__ Wq, const float* __restrict__ bq,
    float* __restrict__ slots_out, float* __restrict__ q_out, int write_q)
{
    __shared__ float u_l[128], h_l[128], nrm_l[128], hid_l[256];
    __shared__ float uu[2][128];
    __shared__ float g6[2][6][128];
    __shared__ float m2[2][128];
    __shared__ float qq[2][128];
    __shared__ float red[4], mv[2];

    const int row = blockIdx.x, tid = threadIdx.x;
    const int d = tid & 127, half = tid >> 7;
    const int bb_ = row / 3, ss = row - bb_ * 3;

    // sum 32 attention partial chunks (split across halves)
    {
        const float* up = upd_part + (((size_t)bb_ * 32 + half * 16) * 3 + ss) * 128 + d;
        float u = 0.f;
#pragma unroll
        for (int c = 0; c < 16; c++) u += up[(size_t)c * 384];
        uu[half][d] = u;
    }
    if (half == 0) h_l[d] = slots_in[row * 128 + d];
    __syncthreads();
    if (half == 0) u_l[d] = uu[0][d] + uu[1][d];
    __syncthreads();

    // GRU gates: thread (d, half) does 64 of 128 k-dims for all 6 gates
    {
        const int ko = half * 64;
        float p6[6] = {0.f, 0.f, 0.f, 0.f, 0.f, 0.f};
#pragma unroll
        for (int g = 0; g < 3; g++) {
            const float4* wi = (const float4*)&Wih[(size_t)(g * 128 + d) * 128 + ko];
            const float4* wh = (const float4*)&Whh[(size_t)(g * 128 + d) * 128 + ko];
            float ai = 0.f, ah_ = 0.f;
#pragma unroll
            for (int i = 0; i < 16; i++) {
                float4 w = wi[i];
                float u0 = u_l[ko + 4*i], u1 = u_l[ko + 4*i+1],
                      u2 = u_l[ko + 4*i+2], u3 = u_l[ko + 4*i+3];
                ai += u0*w.x + u1*w.y + u2*w.z + u3*w.w;
                float4 v = wh[i];
                float h0 = h_l[ko + 4*i], h1 = h_l[ko + 4*i+1],
                      h2 = h_l[ko + 4*i+2], h3 = h_l[ko + 4*i+3];
                ah_ += h0*v.x + h1*v.y + h2*v.z + h3*v.w;
            }
            p6[g] = ai; p6[3 + g] = ah_;
        }
#pragma unroll
        for (int g = 0; g < 6; g++) g6[half][g][d] = p6[g];
    }
    __syncthreads();

    float hprev = h_l[d];
    float ir = bih[d]      + g6[0][0][d] + g6[1][0][d];
    float iz = bih[128+d]  + g6[0][1][d] + g6[1][1][d];
    float in_ = bih[256+d] + g6[0][2][d] + g6[1][2][d];
    float hr = bhh[d]      + g6[0][3][d] + g6[1][3][d];
    float hz = bhh[128+d]  + g6[0][4][d] + g6[1][4][d];
    float hn = bhh[256+d]  + g6[0][5][d] + g6[1][5][d];
    float r = 1.f / (1.f + expf(-(ir + hr)));
    float z = 1.f / (1.f + expf(-(iz + hz)));
    float nn = tanhf(in_ + r * hn);
    float hnew = (1.f - z) * nn + z * hprev;

    // LayerNorm(hnew) with g_m/b_m — reduce on half 0 (waves 0,1)
    if (half == 0) {
        float s = hnew, s2 = hnew * hnew;
#pragma unroll
        for (int off = 32; off >= 1; off >>= 1) {
            s += __shfl_down(s, off, 64); s2 += __shfl_down(s2, off, 64);
        }
        if ((tid & 63) == 0) { red[tid >> 6] = s; red[2 + (tid >> 6)] = s2; }
    }
    __syncthreads();
    if (tid == 0) {
        float S = red[0] + red[1], S2 = red[2] + red[3];
        float m = S * (1.f / 128.f);
        mv[0] = m;
        mv[1] = rsqrtf(S2 * (1.f / 128.f) - m * m + EPS);
    }
    __syncthreads();
    if (half == 0) nrm_l[d] = (hnew - mv[0]) * mv[1] * g_m[d] + b_m[d];
    __syncthreads();

    // MLP1 (H -> 2H) + exact GELU: one output per thread
    {
        float a = b1[tid];
        const float4* wr = (const float4*)&W1[(size_t)tid * 128];
#pragma unroll 8
        for (int i = 0; i < 32; i++) {
            float4 w = wr[i];
            a += nrm_l[4*i]*w.x + nrm_l[4*i+1]*w.y + nrm_l[4*i+2]*w.z + nrm_l[4*i+3]*w.w;
        }
        a = 0.5f * a * (1.f + erff(a * 0.70710678118654752f));
        hid_l[tid] = a;
    }
    __syncthreads();

    // MLP2 (2H -> H): thread (d, half) does half the 256-dot
    {
        const int ko = half * 128;
        const float4* wr = (const float4*)&W2[(size_t)d * 256 + ko];
        float a = 0.f;
#pragma unroll 8
        for (int i = 0; i < 32; i++) {
            float4 w = wr[i];
            a += hid_l[ko+4*i]*w.x + hid_l[ko+4*i+1]*w.y + hid_l[ko+4*i+2]*w.z + hid_l[ko+4*i+3]*w.w;
        }
        m2[half][d] = a;
    }
    __syncthreads();

    float snew = hnew + b2[d] + m2[0][d] + m2[1][d];
    if (half == 0) slots_out[row * 128 + d] = snew;

    if (write_q) {
        // LN_s(snew) then q = . @ Wq^T + bq
        if (half == 0) {
            float s = snew, s2 = snew * snew;
#pragma unroll
            for (int off = 32; off >= 1; off >>= 1) {
                s += __shfl_down(s, off, 64); s2 += __shfl_down(s2, off, 64);
            }
            if ((tid & 63) == 0) { red[tid >> 6] = s; red[2 + (tid >> 6)] = s2; }
        }
        __syncthreads();
        if (tid == 0) {
            float S = red[0] + red[1], S2 = red[2] + red[3];
            float m = S * (1.f / 128.f);
            mv[0] = m;
            mv[1] = rsqrtf(S2 * (1.f / 128.f) - m * m + EPS);
        }
        __syncthreads();
        if (half == 0) nrm_l[d] = (snew - mv[0]) * mv[1] * g_s[d] + b_s[d];
        __syncthreads();
        {
            const int ko = half * 64;
            const float4* wr = (const float4*)&Wq[(size_t)d * 128 + ko];
            float a = 0.f;
#pragma unroll
            for (int i = 0; i < 16; i++) {
                float4 w = wr[i];
                a += nrm_l[ko+4*i]*w.x + nrm_l[ko+4*i+1]*w.y + nrm_l[ko+4*i+2]*w.z + nrm_l[ko+4*i+3]*w.w;
            }
            qq[half][d] = a;
        }
        __syncthreads();
        if (half == 0) q_out[row * 128 + d] = bq[d] + qq[0][d] + qq[1][d];
    }
}

// ============================================================================
extern "C" void kernel_launch(void* const* d_in, const int* in_sizes, int n_in,
                              void* d_out, int out_size, void* d_ws, size_t ws_size,
                              hipStream_t stream)
{
    const float* patch   = (const float*)d_in[0];
    const float* noise   = (const float*)d_in[1];
    const float* slot_mu = (const float*)d_in[2];
    const float* slot_ls = (const float*)d_in[3];
    const float* Wp = (const float*)d_in[4];  const float* bp = (const float*)d_in[5];
    const float* g_in = (const float*)d_in[6]; const float* b_in = (const float*)d_in[7];
    const float* Wq = (const float*)d_in[8];  const float* bq = (const float*)d_in[9];
    const float* Wk = (const float*)d_in[10]; const float* bk = (const float*)d_in[11];
    const float* Wv = (const float*)d_in[12]; const float* bv = (const float*)d_in[13];
    const float* Wih = (const float*)d_in[14]; const float* bih = (const float*)d_in[15];
    const float* Whh = (const float*)d_in[16]; const float* bhh = (const float*)d_in[17];
    const float* g_s = (const float*)d_in[18]; const float* b_s = (const float*)d_in[19];
    const float* W1 = (const float*)d_in[20]; const float* b1 = (const float*)d_in[21];
    const float* W2 = (const float*)d_in[22]; const float* b2 = (const float*)d_in[23];
    const float* g_m = (const float*)d_in[24]; const float* b_m = (const float*)d_in[25];

    float* kbuf = (float*)d_ws;                                   // 16777216 f32
    float* vbuf = kbuf + 16777216;                                // 16777216 f32
    unsigned short* ln_hi = (unsigned short*)(vbuf + 16777216);   // 16777216 bf16
    unsigned short* ln_lo = ln_hi + 16777216;                     // 16777216 bf16
    unsigned short* w_hi  = ln_lo + 16777216;                     // 57344
    unsigned short* w_lo  = w_hi + 57344;                         // 57344
    unsigned short* wp_hi = w_hi,         * wp_lo = w_lo;
    unsigned short* wk_hi = w_hi + 24576, * wk_lo = w_lo + 24576;
    unsigned short* wv_hi = w_hi + 40960, * wv_lo = w_lo + 40960;
    // slots/q/partials alias the inputs(hi/lo) region — dead after gemm_kv.
    float* slots = (float*)ln_hi;                                 // 49152 f32
    float* qbuf  = slots + 49152;                                 // 49152 f32
    float* part  = qbuf + 49152;                                  // 1572864 f32

    float* out_slots = (float*)d_out;                             // (B,K,H)
    float* out_attn  = (float*)d_out + 49152;                     // (B,K,N)

    split_weights_kernel<<<224, 256, 0, stream>>>(Wp, Wk, Wv, w_hi, w_lo);
    gemm1_kernel<<<1024, 512, 0, stream>>>(patch, wp_hi, wp_lo, bp, g_in, b_in,
                                           ln_hi, ln_lo);
    gemm_kv_kernel<<<1024, 512, 0, stream>>>(ln_hi, ln_lo, wk_hi, wk_lo,
                                             wv_hi, wv_lo, bk, bv, kbuf, vbuf);
    init_lnq_kernel<<<384, 128, 0, stream>>>(noise, slot_mu, slot_ls,
                                             g_s, b_s, Wq, bq, slots, qbuf);

    for (int it = 0; it < 3; it++) {
        attn_kernel<<<dim3(32, 128), 256, 0, stream>>>(
            qbuf, kbuf, vbuf, part, out_attn, it == 2 ? 1 : 0);
        slot_update_kernel<<<384, 256, 0, stream>>>(
            slots, part, Wih, bih, Whh, bhh, g_m, b_m, W1, b1, W2, b2,
            g_s, b_s, Wq, bq,
            (it == 2) ? out_slots : slots, qbuf, it == 2 ? 0 : 1);
    }
}